// Round 10
// baseline (140.043 us; speedup 1.0000x reference)
//
#include <hip/hip_runtime.h>

// Problem constants
#define B_    2
#define S_    2048
#define DIN   1024
#define DOUT  1024
#define H_    16
#define HD_   64
#define M_    (B_ * S_)   // 4096 rows total

typedef __bf16 bf16x8 __attribute__((ext_vector_type(8)));
typedef float  f32x4  __attribute__((ext_vector_type(4)));

__device__ __forceinline__ f32x4 MFMA(bf16x8 a, bf16x8 b, f32x4 c) {
    return __builtin_amdgcn_mfma_f32_16x16x32_bf16(a, b, c, 0, 0, 0);
}

// float -> bf16 bits, round-to-nearest-even (epilogue paths)
__device__ __forceinline__ unsigned short f2b(float f) {
    union { float f; unsigned int u; } v; v.f = f;
    unsigned int u = v.u;
    return (unsigned short)((u + 0x7fffu + ((u >> 16) & 1u)) >> 16);
}

// pack two floats into one u32 of bf16 pairs (lo = a, hi = b)
__device__ __forceinline__ unsigned pack2(float a, float b) {
    union { __bf16 h[2]; unsigned u; } cv;
    cv.h[0] = (__bf16)a; cv.h[1] = (__bf16)b;
    return cv.u;
}

// async global->LDS, 16B per lane; LDS dest = wave-uniform base + lane*16
#define GLDS(gp, lp) __builtin_amdgcn_global_load_lds( \
    (const __attribute__((address_space(1))) void*)(gp), \
    (__attribute__((address_space(3))) void*)(lp), 16, 0, 0)

// Q pre-scale: 1/sqrt(64) * log2(e)  (exp2-domain softmax)
#define QSCALE 0.1803368801111204f

// ---- fused converts: x (f32->bf16) + 4 weight transposes (f32 KxN -> bf16 NxK) ----
__global__ __launch_bounds__(256) void k_cvt_all(const float* __restrict__ x,
                                                 const float* __restrict__ Wq,
                                                 const float* __restrict__ Wk,
                                                 const float* __restrict__ Wv,
                                                 const float* __restrict__ Wo,
                                                 unsigned short* __restrict__ xb,
                                                 unsigned short* __restrict__ WqkvT,
                                                 unsigned short* __restrict__ WoT) {
    __shared__ float tile[32][33];
    int bid = blockIdx.x;
    if (bid < 4096) {
        int i = (bid * 256 + threadIdx.x) * 4;
        float4 v = *reinterpret_cast<const float4*>(x + i);
        ushort4 o;
        o.x = f2b(v.x); o.y = f2b(v.y); o.z = f2b(v.z); o.w = f2b(v.w);
        *reinterpret_cast<ushort4*>(xb + i) = o;
        return;
    }
    int wb = bid - 4096;
    int w = wb >> 10;
    int t = wb & 1023;
    const float* src = (w == 0) ? Wq : (w == 1) ? Wk : (w == 2) ? Wv : Wo;
    unsigned short* dst = (w < 3) ? WqkvT + (size_t)w * 1024 * DIN : WoT;
    int n0 = (t & 31) * 32, k0 = (t >> 5) * 32;
    int tx = threadIdx.x & 31, ty = threadIdx.x >> 5;
    for (int i = 0; i < 4; i++)
        tile[ty + i * 8][tx] = src[(size_t)(k0 + ty + i * 8) * DOUT + n0 + tx];
    __syncthreads();
    for (int i = 0; i < 4; i++)
        dst[(size_t)(n0 + ty + i * 8) * DIN + k0 + tx] = f2b(tile[tx][ty + i * 8]);
}

// ---- transpose V per (b,h): [b*S+s][h*HD+hd] -> [(b*H+h)*HD+hd][s] ----
__global__ __launch_bounds__(256) void k_trV(const unsigned short* __restrict__ V,
                                             unsigned short* __restrict__ Vt) {
    __shared__ unsigned short tile[64][72];
    int st = blockIdx.x, bh = blockIdx.y;
    int b = bh >> 4, h = bh & 15;
    int t = threadIdx.x;
    int r = t >> 2, c = (t & 3) << 4;
    const unsigned short* src = V + (size_t)(b * S_ + st * 64 + r) * DOUT + h * HD_ + c;
    *reinterpret_cast<int4*>(&tile[r][c])     = *reinterpret_cast<const int4*>(src);
    *reinterpret_cast<int4*>(&tile[r][c + 8]) = *reinterpret_cast<const int4*>(src + 8);
    __syncthreads();
    unsigned short o[16];
    for (int j = 0; j < 16; j++) o[j] = tile[c + j][r];
    unsigned short* dst = Vt + (size_t)(bh * 64 + r) * S_ + st * 64 + c;
    *reinterpret_cast<int4*>(dst)     = *reinterpret_cast<int4*>(&o[0]);
    *reinterpret_cast<int4*>(dst + 8) = *reinterpret_cast<int4*>(&o[8]);
}

// ---------------- bf16 MFMA GEMM: C[M,N] = A[M,K] @ Bt[N,K]^T ----------------
// 128x128 tile, BK=64, 32KB LDS, global_load_lds staging with T2 XOR swizzle.
// OUT_MODE 0: QKV fused — row-major bf16; Q pre-scaled by QSCALE.
// OUT_MODE 2: f32 out + bias
template <int OUT_MODE>
__global__ __launch_bounds__(256) void k_gemm(const unsigned short* __restrict__ A,
                                              const unsigned short* __restrict__ Bt,
                                              unsigned short* __restrict__ Cq,
                                              unsigned short* __restrict__ Ck,
                                              unsigned short* __restrict__ Cv,
                                              float* __restrict__ Cf,
                                              const float* __restrict__ bias,
                                              int M, int N, int K, int nbx) {
    __shared__ __align__(16) unsigned short As[128 * 64];
    __shared__ __align__(16) unsigned short Bs[128 * 64];

    int nwg = gridDim.x;
    int chunkw = nwg >> 3;
    int bid = blockIdx.x;
    int nid = (bid & 7) * chunkw + (bid >> 3);
    int by = nid / nbx, bx = nid - by * nbx;
    int m0 = by * 128, n0 = bx * 128;

    int tid = threadIdx.x;
    int wid = tid >> 6, lane = tid & 63;
    int wm = wid >> 1, wn = wid & 1;
    int lr = lane & 15, lg = lane >> 4;

    f32x4 acc[4][4] = {};

    int srow = lane >> 3;                       // 0..7 within chunk
    int scol = ((lane & 7) ^ srow) * 8;         // pre-swizzled source col (elements)
    int rsw  = lr & 7;                          // read-side XOR

    for (int k0 = 0; k0 < K; k0 += 64) {
#pragma unroll
        for (int c = 0; c < 4; c++) {
            int chunk = wid * 4 + c;
            int row = chunk * 8 + srow;
            GLDS(A  + (size_t)(m0 + row) * K + k0 + scol, (char*)As + chunk * 1024);
            GLDS(Bt + (size_t)(n0 + row) * K + k0 + scol, (char*)Bs + chunk * 1024);
        }
        __syncthreads();

#pragma unroll
        for (int kk = 0; kk < 2; kk++) {
            bf16x8 af[4], bf[4];
#pragma unroll
            for (int mi = 0; mi < 4; mi++)
                af[mi] = *reinterpret_cast<const bf16x8*>(
                    &As[(wm * 64 + mi * 16 + lr) * 64 + (((kk * 4 + lg) ^ rsw) * 8)]);
#pragma unroll
            for (int ni = 0; ni < 4; ni++)
                bf[ni] = *reinterpret_cast<const bf16x8*>(
                    &Bs[(wn * 64 + ni * 16 + lr) * 64 + (((kk * 4 + lg) ^ rsw) * 8)]);
#pragma unroll
            for (int mi = 0; mi < 4; mi++)
#pragma unroll
                for (int ni = 0; ni < 4; ni++)
                    acc[mi][ni] = MFMA(af[mi], bf[ni], acc[mi][ni]);
        }
        __syncthreads();
    }

    for (int mi = 0; mi < 4; mi++)
        for (int ni = 0; ni < 4; ni++)
            for (int i = 0; i < 4; i++) {
                int row = m0 + wm * 64 + mi * 16 + lg * 4 + i;
                int col = n0 + wn * 64 + ni * 16 + lr;
                float v = acc[mi][ni][i];
                if (OUT_MODE == 2) {
                    Cf[(size_t)row * N + col] = v + bias[col];
                } else {
                    if (col < 1024)       Cq[(size_t)row * 1024 + col] = f2b(v * QSCALE);
                    else if (col < 2048)  Ck[(size_t)row * 1024 + (col - 1024)] = f2b(v);
                    else                  Cv[(size_t)row * 1024 + (col - 2048)] = f2b(v);
                }
            }
}

// ---------------- flash attention (causal), 4-wave paired blocks, 32 rows/wave ----
// grid (16, B*H), 256 threads. Waves 0-1: halves of q-tile 31-p (B); waves 2-3:
// q-tile p (A). Each wave owns 32 q-rows (two 16-row chunks) so every K/V LDS
// fragment read feeds TWO MFMAs (LDS-pipe amortization). KV tiles of 64,
// double-buffered LDS via global_load_lds (pre-swizzled source), counted vmcnt.
// Boundless exp2-softmax, per-lane l accumulation.
__global__ __launch_bounds__(256, 4) void k_attn(const unsigned short* __restrict__ Q,
                                                 const unsigned short* __restrict__ Kg,
                                                 const unsigned short* __restrict__ Vt,
                                                 unsigned short* __restrict__ ctx) {
    int p = blockIdx.x;
    int bh = blockIdx.y;
    int b = bh >> 4, h = bh & 15;
    int tid = threadIdx.x, wid = tid >> 6, lane = tid & 63;
    int lr = lane & 15, lg = lane >> 4;
    int qtB = 31 - p;
    int qt = (wid < 2) ? qtB : p;              // wave's q-tile
    int q0 = qt * 64 + (wid & 1) * 32;         // wave's 32 q-rows

    __shared__ __align__(16) unsigned short Ks[2][64 * 64];   // [kv][hd], swizzled (8KB)
    __shared__ __align__(16) unsigned short Vs[2][64 * 64];   // [hd][s],  swizzled (8KB)
    __shared__ __align__(16) unsigned p_lds32[4][16 * 32];    // per-wave P (2KB, reused per chunk)
    unsigned* pl32 = p_lds32[wid];

    const unsigned short* Qp = Q  + (size_t)b * S_ * DOUT + (size_t)h * HD_;
    const unsigned short* Kp = Kg + (size_t)b * S_ * DOUT + (size_t)h * HD_;
    const unsigned short* Vp = Vt + (size_t)(b * H_ + h) * HD_ * S_;

    bf16x8 qf0a = *reinterpret_cast<const bf16x8*>(&Qp[(size_t)(q0 + lr) * DOUT + lg * 8]);
    bf16x8 qf0b = *reinterpret_cast<const bf16x8*>(&Qp[(size_t)(q0 + lr) * DOUT + 32 + lg * 8]);
    bf16x8 qf1a = *reinterpret_cast<const bf16x8*>(&Qp[(size_t)(q0 + 16 + lr) * DOUT + lg * 8]);
    bf16x8 qf1b = *reinterpret_cast<const bf16x8*>(&Qp[(size_t)(q0 + 16 + lr) * DOUT + 32 + lg * 8]);
    asm volatile("" : "+v"(qf0a), "+v"(qf0b), "+v"(qf1a), "+v"(qf1b));

    // staging: 4 waves x (2 K + 2 V) GLDS of 1KB (8 rows) each per tile.
    int srow = lane >> 3;
    int scol = ((lane & 7) ^ srow) * 8;        // pre-swizzled col (elements)

#define STAGE_KV(buf, t)                                                           \
    {                                                                              \
        int kv0_ = (t) * 64;                                                       \
        for (int cc = 0; cc < 2; cc++) {                                           \
            int ch = wid * 2 + cc;                                                 \
            int krow = ch * 8 + srow;                                              \
            GLDS(Kp + (size_t)(kv0_ + krow) * DOUT + scol,                         \
                 (char*)&Ks[buf][0] + ch * 1024);                                  \
            GLDS(Vp + (size_t)krow * S_ + kv0_ + scol,                             \
                 (char*)&Vs[buf][0] + ch * 1024);                                  \
        }                                                                          \
    }

    STAGE_KV(0, 0)

    f32x4 o0[4] = {}, o1[4] = {};
    float l0 = 0.f, l1 = 0.f;

    int ntile = qtB + 1;
    int rxor = (lr & 7) << 4;
    int qg0 = q0 + lr, qg1 = q0 + 16 + lr;

    for (int t = 0; t < ntile; t++) {
        int cur = t & 1;
        if (t + 1 < ntile) {
            STAGE_KV(cur ^ 1, t + 1)
            asm volatile("s_waitcnt vmcnt(4)" ::: "memory");
        } else {
            asm volatile("s_waitcnt vmcnt(0)" ::: "memory");
        }
        __builtin_amdgcn_s_barrier();

        if (t <= qt) {
            const unsigned short* Kt = Ks[cur];
            const unsigned short* Vl = Vs[cur];
            int kv0 = t * 64;

            // QK^T swapped: mfma(K, Q); each kf read feeds BOTH chunks
            f32x4 s0[4] = {}, s1[4] = {};
            __builtin_amdgcn_s_setprio(1);
#pragma unroll
            for (int nf = 0; nf < 4; nf++)
#pragma unroll
                for (int kk = 0; kk < 2; kk++) {
                    bf16x8 kf = *reinterpret_cast<const bf16x8*>(
                        &Kt[(nf * 16 + lr) * 64 + (((kk * 64 + lg * 16) ^ rxor) >> 1)]);
                    s0[nf] = MFMA(kf, kk ? qf0b : qf0a, s0[nf]);
                    s1[nf] = MFMA(kf, kk ? qf1b : qf1a, s1[nf]);
                }
            __builtin_amdgcn_s_setprio(0);

            if (t == qt) {
#pragma unroll
                for (int nf = 0; nf < 4; nf++)
#pragma unroll
                    for (int i = 0; i < 4; i++) {
                        int kv = kv0 + nf * 16 + lg * 4 + i;
                        if (kv > qg0) s0[nf][i] = -2000.0f;
                        if (kv > qg1) s1[nf][i] = -2000.0f;
                    }
            }

            // boundless softmax chunk0: P = exp2(s), pack bf16, swizzled P-LDS
            bf16x8 pf0[2], pf1[2];
            {
                f32x4 acc = {};
#pragma unroll
                for (int nf = 0; nf < 4; nf++) {
                    f32x4 pv;
#pragma unroll
                    for (int i = 0; i < 4; i++) pv[i] = exp2f(s0[nf][i]);
                    acc += pv;
                    int unit = (nf * 2 + (lg >> 1)) ^ (lr & 7);
                    uint2 wd; wd.x = pack2(pv[0], pv[1]); wd.y = pack2(pv[2], pv[3]);
                    *reinterpret_cast<uint2*>(&pl32[lr * 32 + unit * 4 + (lg & 1) * 2]) = wd;
                }
                l0 += (acc[0] + acc[1]) + (acc[2] + acc[3]);
#pragma unroll
                for (int kvb = 0; kvb < 2; kvb++)
                    pf0[kvb] = *reinterpret_cast<const bf16x8*>(
                        &pl32[lr * 32 + (((kvb * 4 + lg) ^ (lr & 7)) * 4)]);
            }
            // chunk1 (reuses the same 2KB P buffer; DS pipe is in-order per wave)
            {
                f32x4 acc = {};
#pragma unroll
                for (int nf = 0; nf < 4; nf++) {
                    f32x4 pv;
#pragma unroll
                    for (int i = 0; i < 4; i++) pv[i] = exp2f(s1[nf][i]);
                    acc += pv;
                    int unit = (nf * 2 + (lg >> 1)) ^ (lr & 7);
                    uint2 wd; wd.x = pack2(pv[0], pv[1]); wd.y = pack2(pv[2], pv[3]);
                    *reinterpret_cast<uint2*>(&pl32[lr * 32 + unit * 4 + (lg & 1) * 2]) = wd;
                }
                l1 += (acc[0] + acc[1]) + (acc[2] + acc[3]);
#pragma unroll
                for (int kvb = 0; kvb < 2; kvb++)
                    pf1[kvb] = *reinterpret_cast<const bf16x8*>(
                        &pl32[lr * 32 + (((kvb * 4 + lg) ^ (lr & 7)) * 4)]);
            }

            // PV: each vf read feeds BOTH chunks
            __builtin_amdgcn_s_setprio(1);
#pragma unroll
            for (int nd = 0; nd < 4; nd++)
#pragma unroll
                for (int kk = 0; kk < 2; kk++) {
                    bf16x8 vf = *reinterpret_cast<const bf16x8*>(
                        &Vl[(nd * 16 + lr) * 64 + (((kk * 64 + lg * 16) ^ rxor) >> 1)]);
                    o0[nd] = MFMA(pf0[kk], vf, o0[nd]);
                    o1[nd] = MFMA(pf1[kk], vf, o1[nd]);
                }
            __builtin_amdgcn_s_setprio(0);
        }

        __builtin_amdgcn_s_barrier();
    }

    // cross-lane row sums (hoisted out of the KV loop)
    l0 += __shfl_xor(l0, 16, 64);
    l0 += __shfl_xor(l0, 32, 64);
    l1 += __shfl_xor(l1, 16, 64);
    l1 += __shfl_xor(l1, 32, 64);

#pragma unroll
    for (int i = 0; i < 4; i++) {
        float li0 = __shfl(l0, lg * 4 + i, 16);
        float li1 = __shfl(l1, lg * 4 + i, 16);
        float r0 = __builtin_amdgcn_rcpf(li0);
        float r1 = __builtin_amdgcn_rcpf(li1);
#pragma unroll
        for (int nd = 0; nd < 4; nd++) {
            ((__bf16*)ctx)[((size_t)b * S_ + q0 + lg * 4 + i) * DOUT + h * HD_ + nd * 16 + lr] =
                (__bf16)(o0[nd][i] * r0);
            ((__bf16*)ctx)[((size_t)b * S_ + q0 + 16 + lg * 4 + i) * DOUT + h * HD_ + nd * 16 + lr] =
                (__bf16)(o1[nd][i] * r1);
        }
    }
#undef STAGE_KV
}

extern "C" void kernel_launch(void* const* d_in, const int* in_sizes, int n_in,
                              void* d_out, int out_size, void* d_ws, size_t ws_size,
                              hipStream_t stream) {
    const float* x  = (const float*)d_in[0];
    const float* Wq = (const float*)d_in[1];
    const float* Wk = (const float*)d_in[2];
    const float* Wv = (const float*)d_in[3];
    const float* Wo = (const float*)d_in[4];
    const float* bo = (const float*)d_in[5];
    float* out = (float*)d_out;
    char* ws = (char*)d_ws;
    const size_t MB = 1u << 20;

    unsigned short* xb    = (unsigned short*)(ws);
    unsigned short* Vtb   = (unsigned short*)(ws);            // reuse of xb
    unsigned short* WqkvT = (unsigned short*)(ws + 8 * MB);
    unsigned short* WoT   = (unsigned short*)(ws + 14 * MB);
    unsigned short* Qb    = (unsigned short*)(ws + 16 * MB);
    unsigned short* Kb    = (unsigned short*)(ws + 24 * MB);
    unsigned short* Vb    = (unsigned short*)(ws + 32 * MB);
    unsigned short* ctx   = Vb;                               // reuse of Vb

    (void)in_sizes; (void)n_in; (void)out_size; (void)ws_size;

    // fused converts: x -> bf16, 4 weights -> bf16 transposed
    k_cvt_all<<<8192, 256, 0, stream>>>(x, Wq, Wk, Wv, Wo, xb, WqkvT, WoT);

    // fused QKV projection (Q pre-scaled by QSCALE)
    k_gemm<0><<<768, 256, 0, stream>>>(xb, WqkvT, Qb, Kb, Vb, nullptr, nullptr,
                                       M_, 3072, DIN, 24);

    dim3 gt(S_ / 64, B_ * H_);
    k_trV<<<gt, 256, 0, stream>>>(Vb, Vtb);

    // causal flash attention: 4-wave paired blocks, 32 rows/wave
    dim3 ga(16, B_ * H_);
    k_attn<<<ga, 256, 0, stream>>>(Qb, Kb, Vtb, ctx);

    k_gemm<2><<<256, 256, 0, stream>>>(ctx, WoT, nullptr, nullptr, nullptr,
                                       out, bo, M_, DOUT, DOUT, 8);
}

// Round 11
// 112.770 us; speedup vs baseline: 1.2418x; 1.2418x over previous
//
#include <hip/hip_runtime.h>

// Problem constants
#define B_    2
#define S_    2048
#define DIN   1024
#define DOUT  1024
#define H_    16
#define HD_   64
#define M_    (B_ * S_)   // 4096 rows total

typedef __bf16 bf16x8 __attribute__((ext_vector_type(8)));
typedef float  f32x4  __attribute__((ext_vector_type(4)));

__device__ __forceinline__ f32x4 MFMA(bf16x8 a, bf16x8 b, f32x4 c) {
    return __builtin_amdgcn_mfma_f32_16x16x32_bf16(a, b, c, 0, 0, 0);
}

// float -> bf16 bits, round-to-nearest-even (epilogue paths)
__device__ __forceinline__ unsigned short f2b(float f) {
    union { float f; unsigned int u; } v; v.f = f;
    unsigned int u = v.u;
    return (unsigned short)((u + 0x7fffu + ((u >> 16) & 1u)) >> 16);
}

// pack two floats into one u32 of bf16 pairs (lo = a, hi = b)
__device__ __forceinline__ unsigned pack2(float a, float b) {
    union { __bf16 h[2]; unsigned u; } cv;
    cv.h[0] = (__bf16)a; cv.h[1] = (__bf16)b;
    return cv.u;
}

// async global->LDS, 16B per lane; LDS dest = wave-uniform base + lane*16
#define GLDS(gp, lp) __builtin_amdgcn_global_load_lds( \
    (const __attribute__((address_space(1))) void*)(gp), \
    (__attribute__((address_space(3))) void*)(lp), 16, 0, 0)

// Q pre-scale: 1/sqrt(64) * log2(e)  (exp2-domain softmax)
#define QSCALE 0.1803368801111204f

// ---- fused converts: x (f32->bf16) + 4 weight transposes (f32 KxN -> bf16 NxK) ----
__global__ __launch_bounds__(256) void k_cvt_all(const float* __restrict__ x,
                                                 const float* __restrict__ Wq,
                                                 const float* __restrict__ Wk,
                                                 const float* __restrict__ Wv,
                                                 const float* __restrict__ Wo,
                                                 unsigned short* __restrict__ xb,
                                                 unsigned short* __restrict__ WqkvT,
                                                 unsigned short* __restrict__ WoT) {
    __shared__ float tile[32][33];
    int bid = blockIdx.x;
    if (bid < 4096) {
        int i = (bid * 256 + threadIdx.x) * 4;
        float4 v = *reinterpret_cast<const float4*>(x + i);
        ushort4 o;
        o.x = f2b(v.x); o.y = f2b(v.y); o.z = f2b(v.z); o.w = f2b(v.w);
        *reinterpret_cast<ushort4*>(xb + i) = o;
        return;
    }
    int wb = bid - 4096;
    int w = wb >> 10;
    int t = wb & 1023;
    const float* src = (w == 0) ? Wq : (w == 1) ? Wk : (w == 2) ? Wv : Wo;
    unsigned short* dst = (w < 3) ? WqkvT + (size_t)w * 1024 * DIN : WoT;
    int n0 = (t & 31) * 32, k0 = (t >> 5) * 32;
    int tx = threadIdx.x & 31, ty = threadIdx.x >> 5;
    for (int i = 0; i < 4; i++)
        tile[ty + i * 8][tx] = src[(size_t)(k0 + ty + i * 8) * DOUT + n0 + tx];
    __syncthreads();
    for (int i = 0; i < 4; i++)
        dst[(size_t)(n0 + ty + i * 8) * DIN + k0 + tx] = f2b(tile[tx][ty + i * 8]);
}

// ---- transpose V per (b,h): [b*S+s][h*HD+hd] -> [(b*H+h)*HD+hd][s] ----
__global__ __launch_bounds__(256) void k_trV(const unsigned short* __restrict__ V,
                                             unsigned short* __restrict__ Vt) {
    __shared__ unsigned short tile[64][72];
    int st = blockIdx.x, bh = blockIdx.y;
    int b = bh >> 4, h = bh & 15;
    int t = threadIdx.x;
    int r = t >> 2, c = (t & 3) << 4;
    const unsigned short* src = V + (size_t)(b * S_ + st * 64 + r) * DOUT + h * HD_ + c;
    *reinterpret_cast<int4*>(&tile[r][c])     = *reinterpret_cast<const int4*>(src);
    *reinterpret_cast<int4*>(&tile[r][c + 8]) = *reinterpret_cast<const int4*>(src + 8);
    __syncthreads();
    unsigned short o[16];
    for (int j = 0; j < 16; j++) o[j] = tile[c + j][r];
    unsigned short* dst = Vt + (size_t)(bh * 64 + r) * S_ + st * 64 + c;
    *reinterpret_cast<int4*>(dst)     = *reinterpret_cast<int4*>(&o[0]);
    *reinterpret_cast<int4*>(dst + 8) = *reinterpret_cast<int4*>(&o[8]);
}

// ---------------- bf16 MFMA GEMM: C[M,N] = A[M,K] @ Bt[N,K]^T ----------------
// BM x 128 tile (BM = 128 or 64), BK=64, global_load_lds staging with T2 XOR
// swizzle (pre-swizzled source + swizzled ds_read, both sides).
// OUT_MODE 0: QKV fused — row-major bf16; Q pre-scaled by QSCALE.
// OUT_MODE 2: f32 out + bias
template <int OUT_MODE, int BM>
__global__ __launch_bounds__(256) void k_gemm(const unsigned short* __restrict__ A,
                                              const unsigned short* __restrict__ Bt,
                                              unsigned short* __restrict__ Cq,
                                              unsigned short* __restrict__ Ck,
                                              unsigned short* __restrict__ Cv,
                                              float* __restrict__ Cf,
                                              const float* __restrict__ bias,
                                              int M, int N, int K, int nbx) {
    constexpr int MI = BM / 32;   // M-frags per wave
    __shared__ __align__(16) unsigned short As[BM * 64];
    __shared__ __align__(16) unsigned short Bs[128 * 64];

    int nwg = gridDim.x;
    int chunkw = nwg >> 3;
    int bid = blockIdx.x;
    int nid = (bid & 7) * chunkw + (bid >> 3);
    int by = nid / nbx, bx = nid - by * nbx;
    int m0 = by * BM, n0 = bx * 128;

    int tid = threadIdx.x;
    int wid = tid >> 6, lane = tid & 63;
    int wm = wid >> 1, wn = wid & 1;
    int lr = lane & 15, lg = lane >> 4;

    f32x4 acc[MI][4] = {};

    int srow = lane >> 3;                       // 0..7 within chunk
    int scol = ((lane & 7) ^ srow) * 8;         // pre-swizzled source col (elements)
    int rsw  = lr & 7;                          // read-side XOR

    for (int k0 = 0; k0 < K; k0 += 64) {
#pragma unroll
        for (int c = 0; c < MI; c++) {
            int chunk = wid * MI + c;
            int row = chunk * 8 + srow;
            GLDS(A + (size_t)(m0 + row) * K + k0 + scol, (char*)As + chunk * 1024);
        }
#pragma unroll
        for (int c = 0; c < 4; c++) {
            int chunk = wid * 4 + c;
            int row = chunk * 8 + srow;
            GLDS(Bt + (size_t)(n0 + row) * K + k0 + scol, (char*)Bs + chunk * 1024);
        }
        __syncthreads();

#pragma unroll
        for (int kk = 0; kk < 2; kk++) {
            bf16x8 af[MI], bf[4];
#pragma unroll
            for (int mi = 0; mi < MI; mi++)
                af[mi] = *reinterpret_cast<const bf16x8*>(
                    &As[(wm * (BM / 2) + mi * 16 + lr) * 64 + (((kk * 4 + lg) ^ rsw) * 8)]);
#pragma unroll
            for (int ni = 0; ni < 4; ni++)
                bf[ni] = *reinterpret_cast<const bf16x8*>(
                    &Bs[(wn * 64 + ni * 16 + lr) * 64 + (((kk * 4 + lg) ^ rsw) * 8)]);
#pragma unroll
            for (int mi = 0; mi < MI; mi++)
#pragma unroll
                for (int ni = 0; ni < 4; ni++)
                    acc[mi][ni] = MFMA(af[mi], bf[ni], acc[mi][ni]);
        }
        __syncthreads();
    }

    for (int mi = 0; mi < MI; mi++)
        for (int ni = 0; ni < 4; ni++)
            for (int i = 0; i < 4; i++) {
                int row = m0 + wm * (BM / 2) + mi * 16 + lg * 4 + i;
                int col = n0 + wn * 64 + ni * 16 + lr;
                float v = acc[mi][ni][i];
                if (OUT_MODE == 2) {
                    Cf[(size_t)row * N + col] = v + bias[col];
                } else {
                    if (col < 1024)       Cq[(size_t)row * 1024 + col] = f2b(v * QSCALE);
                    else if (col < 2048)  Ck[(size_t)row * 1024 + (col - 1024)] = f2b(v);
                    else                  Cv[(size_t)row * 1024 + (col - 2048)] = f2b(v);
                }
            }
}

// ---- one attn tile-unit: 16 q-rows x 64 kv. QK^T swapped (mfma(K,Q)),
// boundless exp2-softmax (no max tracking), P via per-wave swizzled LDS, PV.
__device__ __forceinline__ void attn_unit(const unsigned short* __restrict__ Kt,
                                          const unsigned short* __restrict__ Vl,
                                          unsigned* __restrict__ pl32,
                                          bf16x8 qf0, bf16x8 qf1,
                                          f32x4 (&o)[4], float& l,
                                          int qg, int kv0, bool diag,
                                          int lr, int lg, int rxor) {
    f32x4 s[4] = {};
    __builtin_amdgcn_s_setprio(1);
#pragma unroll
    for (int nf = 0; nf < 4; nf++)
#pragma unroll
        for (int kk = 0; kk < 2; kk++) {
            bf16x8 kf = *reinterpret_cast<const bf16x8*>(
                &Kt[(nf * 16 + lr) * 64 + (((kk * 64 + lg * 16) ^ rxor) >> 1)]);
            s[nf] = MFMA(kf, kk ? qf1 : qf0, s[nf]);
        }
    __builtin_amdgcn_s_setprio(0);

    if (diag) {
#pragma unroll
        for (int nf = 0; nf < 4; nf++)
#pragma unroll
            for (int i = 0; i < 4; i++)
                if (kv0 + nf * 16 + lg * 4 + i > qg) s[nf][i] = -2000.0f;
    }

    f32x4 acc = {};
#pragma unroll
    for (int nf = 0; nf < 4; nf++) {
        f32x4 pv;
#pragma unroll
        for (int i = 0; i < 4; i++) pv[i] = exp2f(s[nf][i]);
        acc += pv;
        int unit = (nf * 2 + (lg >> 1)) ^ (lr & 7);
        uint2 wd; wd.x = pack2(pv[0], pv[1]); wd.y = pack2(pv[2], pv[3]);
        *reinterpret_cast<uint2*>(&pl32[lr * 32 + unit * 4 + (lg & 1) * 2]) = wd;
    }
    l += (acc[0] + acc[1]) + (acc[2] + acc[3]);

    bf16x8 pf[2];
#pragma unroll
    for (int kvb = 0; kvb < 2; kvb++)
        pf[kvb] = *reinterpret_cast<const bf16x8*>(
            &pl32[lr * 32 + (((kvb * 4 + lg) ^ (lr & 7)) * 4)]);

    __builtin_amdgcn_s_setprio(1);
#pragma unroll
    for (int nd = 0; nd < 4; nd++)
#pragma unroll
        for (int kk = 0; kk < 2; kk++) {
            bf16x8 vf = *reinterpret_cast<const bf16x8*>(
                &Vl[(nd * 16 + lr) * 64 + (((kk * 64 + lg * 16) ^ rxor) >> 1)]);
            o[nd] = MFMA(pf[kk], vf, o[nd]);
        }
    __builtin_amdgcn_s_setprio(0);
}

// ---------------- flash attention (causal), fully wave-balanced ----------------
// grid (16, B*H), 512 threads. Block p owns q-tiles A=p and B=31-p.
// Boundless softmax => O,l are pure sums => KV range splittable across waves:
//   group1 (waves 0-3): B-chunk (wi), kv tiles 0..15   (never diagonal)
//   group2 (waves 4-7): A-chunk (wi), kv tiles 0..p, THEN B-chunk kv 16..31-p
// Every wave: 16 or 17 tile-units (~97% busy). Two independent double-buffered
// LDS staging streams; B partials merged via LDS adds at the end.
__global__ __launch_bounds__(512, 4) void k_attn(const unsigned short* __restrict__ Q,
                                                 const unsigned short* __restrict__ Kg,
                                                 const unsigned short* __restrict__ Vt,
                                                 unsigned short* __restrict__ ctx) {
    int p = blockIdx.x;
    int bh = blockIdx.y;
    int b = bh >> 4, h = bh & 15;
    int tid = threadIdx.x, wid = tid >> 6, lane = tid & 63;
    int lr = lane & 15, lg = lane >> 4;
    int g = wid >> 2, wi = wid & 3;
    int qtB = 31 - p;

    __shared__ __align__(16) unsigned short Ks1[2][64 * 64];   // group1 stream K
    __shared__ __align__(16) unsigned short Vs1[2][64 * 64];   // group1 stream V
    __shared__ __align__(16) unsigned short Ks2[2][64 * 64];   // group2 stream K
    __shared__ __align__(16) unsigned short Vs2[2][64 * 64];   // group2 stream V
    __shared__ __align__(16) unsigned p_lds32[8][16 * 32];     // per-wave P
    unsigned* pl32 = p_lds32[wid];

    const unsigned short* Qp = Q  + (size_t)b * S_ * DOUT + (size_t)h * HD_;
    const unsigned short* Kp = Kg + (size_t)b * S_ * DOUT + (size_t)h * HD_;
    const unsigned short* Vp = Vt + (size_t)(b * H_ + h) * HD_ * S_;

    int q0B = qtB * 64 + wi * 16;
    int q0A = p * 64 + wi * 16;

    bf16x8 qB0 = *reinterpret_cast<const bf16x8*>(&Qp[(size_t)(q0B + lr) * DOUT + lg * 8]);
    bf16x8 qB1 = *reinterpret_cast<const bf16x8*>(&Qp[(size_t)(q0B + lr) * DOUT + 32 + lg * 8]);
    bf16x8 qA0 = {}, qA1 = {};
    if (g == 1) {
        qA0 = *reinterpret_cast<const bf16x8*>(&Qp[(size_t)(q0A + lr) * DOUT + lg * 8]);
        qA1 = *reinterpret_cast<const bf16x8*>(&Qp[(size_t)(q0A + lr) * DOUT + 32 + lg * 8]);
    }
    asm volatile("" : "+v"(qB0), "+v"(qB1));

    // staging: each group's 4 waves stage their own stream; 2K + 2V GLDS/lane.
    int srow = lane >> 3;
    int scol = ((lane & 7) ^ srow) * 8;        // pre-swizzled col (elements)

#define STAGE(KsX, VsX, buf, t)                                                    \
    {                                                                              \
        int kv0_ = (t) * 64;                                                       \
        for (int cc = 0; cc < 2; cc++) {                                           \
            int ch = wi * 2 + cc;                                                  \
            int krow = ch * 8 + srow;                                              \
            GLDS(Kp + (size_t)(kv0_ + krow) * DOUT + scol,                         \
                 (char*)&KsX[buf][0] + ch * 1024);                                 \
            GLDS(Vp + (size_t)krow * S_ + kv0_ + scol,                             \
                 (char*)&VsX[buf][0] + ch * 1024);                                 \
        }                                                                          \
    }

    if (g == 0) STAGE(Ks1, Vs1, 0, 0)
    else        STAGE(Ks2, Vs2, 0, 0)

    f32x4 oB[4] = {}, oA[4] = {};
    float lB = 0.f, lA = 0.f;
    int rxor = (lr & 7) << 4;
    int qgB = q0B + lr, qgA = q0A + lr;

    for (int u = 0; u <= 16; u++) {
        if (g == 0) {
            if (u < 15) {
                STAGE(Ks1, Vs1, (u + 1) & 1, u + 1)
                asm volatile("s_waitcnt vmcnt(4)" ::: "memory");
            } else {
                asm volatile("s_waitcnt vmcnt(0)" ::: "memory");
            }
        } else {
            if (u < 16) {
                int nt = (u + 1 <= p) ? (u + 1) : (u + 16 - p);
                STAGE(Ks2, Vs2, (u + 1) & 1, nt)
                asm volatile("s_waitcnt vmcnt(4)" ::: "memory");
            } else {
                asm volatile("s_waitcnt vmcnt(0)" ::: "memory");
            }
        }
        __builtin_amdgcn_s_barrier();

        if (g == 0) {
            if (u <= 15)
                attn_unit(Ks1[u & 1], Vs1[u & 1], pl32, qB0, qB1, oB, lB,
                          qgB, u * 64, false, lr, lg, rxor);
        } else {
            if (u <= p)
                attn_unit(Ks2[u & 1], Vs2[u & 1], pl32, qA0, qA1, oA, lA,
                          qgA, u * 64, u == p, lr, lg, rxor);
            else {
                int t = u + 15 - p;
                attn_unit(Ks2[u & 1], Vs2[u & 1], pl32, qB0, qB1, oB, lB,
                          qgB, t * 64, t == qtB, lr, lg, rxor);
            }
        }
        __builtin_amdgcn_s_barrier();
    }

    // ---- merge group2's B partials into group1, write outputs ----
    float* mO = (float*)&Ks1[0][0];   // [4][64][16] f32 = 16KB (loop done; safe)
    float* mL = (float*)&Vs1[0][0];   // [4][64]

    if (g == 1) {
        // finalize + store A-chunk
        lA += __shfl_xor(lA, 16, 64);
        lA += __shfl_xor(lA, 32, 64);
#pragma unroll
        for (int i = 0; i < 4; i++) {
            float li = __shfl(lA, lg * 4 + i, 16);
            float r = __builtin_amdgcn_rcpf(li);
#pragma unroll
            for (int nd = 0; nd < 4; nd++)
                ((__bf16*)ctx)[((size_t)b * S_ + q0A + lg * 4 + i) * DOUT + h * HD_ + nd * 16 + lr] =
                    (__bf16)(oA[nd][i] * r);
        }
        // publish B partials
        int base = (wi * 64 + lane) * 16;
#pragma unroll
        for (int nd = 0; nd < 4; nd++)
#pragma unroll
            for (int i = 0; i < 4; i++)
                mO[base + nd * 4 + i] = oB[nd][i];
        mL[wi * 64 + lane] = lB;
    }
    asm volatile("s_waitcnt lgkmcnt(0)" ::: "memory");
    __builtin_amdgcn_s_barrier();
    if (g == 0) {
        int base = (wi * 64 + lane) * 16;
#pragma unroll
        for (int nd = 0; nd < 4; nd++)
#pragma unroll
            for (int i = 0; i < 4; i++)
                oB[nd][i] += mO[base + nd * 4 + i];
        lB += mL[wi * 64 + lane];
        lB += __shfl_xor(lB, 16, 64);
        lB += __shfl_xor(lB, 32, 64);
#pragma unroll
        for (int i = 0; i < 4; i++) {
            float li = __shfl(lB, lg * 4 + i, 16);
            float r = __builtin_amdgcn_rcpf(li);
#pragma unroll
            for (int nd = 0; nd < 4; nd++)
                ((__bf16*)ctx)[((size_t)b * S_ + q0B + lg * 4 + i) * DOUT + h * HD_ + nd * 16 + lr] =
                    (__bf16)(oB[nd][i] * r);
        }
    }
#undef STAGE
}

extern "C" void kernel_launch(void* const* d_in, const int* in_sizes, int n_in,
                              void* d_out, int out_size, void* d_ws, size_t ws_size,
                              hipStream_t stream) {
    const float* x  = (const float*)d_in[0];
    const float* Wq = (const float*)d_in[1];
    const float* Wk = (const float*)d_in[2];
    const float* Wv = (const float*)d_in[3];
    const float* Wo = (const float*)d_in[4];
    const float* bo = (const float*)d_in[5];
    float* out = (float*)d_out;
    char* ws = (char*)d_ws;
    const size_t MB = 1u << 20;

    unsigned short* xb    = (unsigned short*)(ws);
    unsigned short* Vtb   = (unsigned short*)(ws);            // reuse of xb
    unsigned short* WqkvT = (unsigned short*)(ws + 8 * MB);
    unsigned short* WoT   = (unsigned short*)(ws + 14 * MB);
    unsigned short* Qb    = (unsigned short*)(ws + 16 * MB);
    unsigned short* Kb    = (unsigned short*)(ws + 24 * MB);
    unsigned short* Vb    = (unsigned short*)(ws + 32 * MB);
    unsigned short* ctx   = Vb;                               // reuse of Vb

    (void)in_sizes; (void)n_in; (void)out_size; (void)ws_size;

    // fused converts: x -> bf16, 4 weights -> bf16 transposed
    k_cvt_all<<<8192, 256, 0, stream>>>(x, Wq, Wk, Wv, Wo, xb, WqkvT, WoT);

    // fused QKV projection (Q pre-scaled by QSCALE)
    k_gemm<0, 128><<<768, 256, 0, stream>>>(xb, WqkvT, Qb, Kb, Vb, nullptr, nullptr,
                                            M_, 3072, DIN, 24);

    dim3 gt(S_ / 64, B_ * H_);
    k_trV<<<gt, 256, 0, stream>>>(Vb, Vtb);

    // causal flash attention: wave-balanced two-stream schedule
    dim3 ga(16, B_ * H_);
    k_attn<<<ga, 512, 0, stream>>>(Qb, Kb, Vtb, ctx);

    // output projection + bias (BM=64 tile -> 512 blocks = 2/CU)
    k_gemm<2, 64><<<512, 256, 0, stream>>>(ctx, WoT, nullptr, nullptr, nullptr,
                                           out, bo, M_, DOUT, DOUT, 8);
}